// Round 8
// baseline (26.145 us; speedup 1.0000x reference)
//
#include <hip/hip_runtime.h>
#include <hip/hip_bf16.h>

// B=4, N=512, D=64. ONE kernel, 256 blocks x 1024 thr (16 waves), no inter-block deps.
// R8 = R7's MFMA c-tile + ZERO divergent global loads (all weights via coalesced LDS).
//   P0: stage Wmsg fp32 -> wm[64][130], Wn[:, :64] -> wn1[64][66], maskf (coalesced)
//   bWj regs: extracted per-wave from wm LDS (cols 64..127), bf16
//   P1 (tid<512, VALU, exact fp32): a_s[r][m] = bmsg + V[row]·Wi[m] ; o1(reg) = bn + V[row]·Wn1[m]
//   P2: vt = bf16(V half-batch) XOR-swizzled LDS (overlays wm); acc = mfma(V_j, Wj_m)
//       p[r] += max(acc + maskf_j, -a[r][m])   (relu(a+c)=max(c,-a)+a; masked j -> -a -> 0)
//   reduce: shfl_xor(16,32) -> part[8][8][64] (overlays wn1) -> agg = sum + 512*a, i-mask
//   epi: wn2 staged into freed vt region; out = relu(o1 + agg·Wn2) (VALU, LDS broadcast)

typedef float  f32x4  __attribute__((ext_vector_type(4)));
typedef float  v2f    __attribute__((ext_vector_type(2)));
typedef short  bf16x8 __attribute__((ext_vector_type(8)));
typedef unsigned short u16;

__device__ __forceinline__ v2f pk_add(v2f a, v2f b) {
    v2f d; asm("v_pk_add_f32 %0, %1, %2" : "=v"(d) : "v"(a), "v"(b)); return d;
}
__device__ __forceinline__ u16 bf16_of(float x) {
    __hip_bfloat16 b = __float2bfloat16(x);
    return *(u16*)&b;
}
__device__ __forceinline__ bf16x8 cvt8(const float* p) {
    float4 x = *(const float4*)p, y = *(const float4*)(p + 4);
    float v[8] = {x.x, x.y, x.z, x.w, y.x, y.y, y.z, y.w};
    bf16x8 r;
#pragma unroll
    for (int i = 0; i < 8; ++i) r[i] = (short)bf16_of(v[i]);
    return r;
}

// LDS floats (14144 f = 56576 B):
//   @0     wm fp32[64][130] (8320) | overlay: vt u16[256][64] swz (8192 f) | overlay: wn2 fp32[64][66] (4224)
//   @8320  wn1 fp32[64][66] (4224) | overlay: part f32[8][8][64] (4096)
//   @12544 maskf (512) | @13056 a_s[8][68] (544) | @13600 agg_s[8][68] (544)
__global__ __launch_bounds__(1024) void fused_gb8(
    const float* __restrict__ V, const int* __restrict__ mask,
    const float* __restrict__ Wmsg, const float* __restrict__ bmsg,
    const float* __restrict__ Wn, const float* __restrict__ bn,
    float* __restrict__ out)
{
    __shared__ float buf[14144];
    float* wm    = buf;                 // [64][130]
    u16*   vt    = (u16*)buf;           // [256][64] bf16, XOR-swizzled
    float* wn2   = buf;                 // [64][66] (epi overlay)
    float* wn1   = buf + 8320;          // [64][66]
    float* part  = buf + 8320;          // [8][8][64]
    float* maskf = buf + 12544;
    float* a_s   = buf + 13056;         // [8][68]
    float* agg_s = buf + 13600;         // [8][68]

    const int tid  = threadIdx.x;
    const int l    = tid & 63;
    const int w    = tid >> 6;
    const int g    = l >> 4;            // 0..3 k-group
    const int l15  = l & 15;
    const int mh   = w >> 3;            // 0..1 m-half
    const int jg   = w & 7;             // 0..7 j-group
    const int bb   = blockIdx.x >> 6;   // batch
    const int i0   = blockIdx.x * 8;
    const int iloc = (blockIdx.x & 63) * 8;
    const float* Vb = V + (size_t)bb * 512 * 64;

    // ---- P0: coalesced staging ----
#pragma unroll
    for (int k = 0; k < 2; ++k) {
        int f4 = tid + k * 1024;                 // 0..2047
        int mm = f4 >> 5, dd = (f4 & 31) << 2;
        *(float4*)&wm[mm * 130 + dd] = ((const float4*)Wmsg)[f4];
    }
    {
        int oo = tid >> 4, kk = (tid & 15) << 2;
        *(float4*)&wn1[oo * 66 + kk] = *(const float4*)&Wn[oo * 128 + kk];
    }
    if (tid < 512) maskf[tid] = mask[bb * 512 + tid] ? 0.f : -1e30f;
    __syncthreads();                             // S0

    // ---- bWj fragments from LDS (all waves, one-time) ----
    bf16x8 bWj[2][2];
#pragma unroll
    for (int mtp = 0; mtp < 2; ++mtp) {
        int mrow = (mh * 2 + mtp) * 16 + l15;
#pragma unroll
        for (int kh = 0; kh < 2; ++kh)
            bWj[mtp][kh] = cvt8(&wm[mrow * 130 + 64 + (g << 3) + (kh << 5)]);
    }

    // ---- P1: exact fp32 a and o1 (waves 0-7, 1 row each) ----
    float o1 = 0.f;
    if (tid < 512) {
        int m = l;
        int row = __builtin_amdgcn_readfirstlane(i0 + w);   // wave-uniform -> scalar loads
        const float* v = V + row * 64;
        float sa = bmsg[m], so = bn[m];
#pragma unroll
        for (int d0 = 0; d0 < 64; d0 += 4) {
            float4 va = *(const float4*)&v[d0];
            float4 wa = *(float4*)&wm[m * 130 + d0];
            float4 wo = *(float4*)&wn1[m * 66 + d0];
            sa = fmaf(va.x, wa.x, sa); sa = fmaf(va.y, wa.y, sa);
            sa = fmaf(va.z, wa.z, sa); sa = fmaf(va.w, wa.w, sa);
            so = fmaf(va.x, wo.x, so); so = fmaf(va.y, wo.y, so);
            so = fmaf(va.z, wo.z, so); so = fmaf(va.w, wo.w, so);
        }
        a_s[w * 68 + m] = sa;
        o1 = so;
    }
    __syncthreads();                             // S1: wm/wn1 reads done, a_s ready

    // ---- stage vt (half h) -> bf16, XOR-swizzled (overlays wm) ----
    auto stage_half = [&](int h) {
#pragma unroll
        for (int q = 0; q < 4; ++q) {
            int idx = tid + q * 1024;            // 0..4095
            int row = idx >> 4;                  // 0..255
            int c4  = (idx & 15) << 2;           // float col 0,4,..,60
            float4 v4 = *(const float4*)&Vb[(h * 256 + row) * 64 + c4];
            ushort4 us;
            us.x = bf16_of(v4.x); us.y = bf16_of(v4.y);
            us.z = bf16_of(v4.z); us.w = bf16_of(v4.w);
            int byte = (row << 7) + ((c4 << 1) ^ ((row & 7) << 4));
            *(ushort4*)((char*)vt + byte) = us;
        }
    };

    float nar[2][8];
#pragma unroll
    for (int mtp = 0; mtp < 2; ++mtp) {
        int m = (mh * 2 + mtp) * 16 + l15;
#pragma unroll
        for (int r = 0; r < 8; ++r) nar[mtp][r] = -a_s[r * 68 + m];
    }
    v2f p2[2][8];
#pragma unroll
    for (int mtp = 0; mtp < 2; ++mtp)
#pragma unroll
        for (int r = 0; r < 8; ++r) p2[mtp][r] = (v2f){0.f, 0.f};

    auto compute_half = [&](int h) {
#pragma unroll
        for (int t = 0; t < 2; ++t) {
            int jbase = jg * 32 + t * 16;
            bf16x8 aV[2];
#pragma unroll
            for (int kh = 0; kh < 2; ++kh) {
                int jrow = jbase + l15;
                int byte = (jrow << 7) + ((((g << 4) + (kh << 6))) ^ ((jrow & 7) << 4));
                aV[kh] = *(const bf16x8*)((const char*)vt + byte);
            }
            f32x4 mf = *(const f32x4*)&maskf[h * 256 + jbase + g * 4];  // lane's 4 j's
#pragma unroll
            for (int mtp = 0; mtp < 2; ++mtp) {
                f32x4 acc = {0.f, 0.f, 0.f, 0.f};
                acc = __builtin_amdgcn_mfma_f32_16x16x32_bf16(aV[0], bWj[mtp][0], acc, 0, 0, 0);
                acc = __builtin_amdgcn_mfma_f32_16x16x32_bf16(aV[1], bWj[mtp][1], acc, 0, 0, 0);
                float cm0 = acc[0] + mf[0], cm1 = acc[1] + mf[1];
                float cm2 = acc[2] + mf[2], cm3 = acc[3] + mf[3];
#pragma unroll
                for (int r = 0; r < 8; ++r) {
                    float n = nar[mtp][r];
                    v2f mxa = { fmaxf(cm0, n), fmaxf(cm1, n) };
                    v2f mxb = { fmaxf(cm2, n), fmaxf(cm3, n) };
                    p2[mtp][r] = pk_add(p2[mtp][r], mxa);
                    p2[mtp][r] = pk_add(p2[mtp][r], mxb);
                }
            }
        }
    };

    stage_half(0);
    __syncthreads();                             // S2: vt h0 ready
    compute_half(0);
    __syncthreads();                             // S3: vt h0 reads done
    stage_half(1);
    __syncthreads();                             // S4: vt h1 ready
    compute_half(1);

    // in-wave reduce over g (lane^16, ^32); write part[jg][r][m] (wn1 region, free)
    float pr[2][8];
#pragma unroll
    for (int mtp = 0; mtp < 2; ++mtp)
#pragma unroll
        for (int r = 0; r < 8; ++r) {
            float v = p2[mtp][r].x + p2[mtp][r].y;
            v += __shfl_xor(v, 16);
            v += __shfl_xor(v, 32);
            pr[mtp][r] = v;
        }
    if (l < 16) {
#pragma unroll
        for (int mtp = 0; mtp < 2; ++mtp)
#pragma unroll
            for (int r = 0; r < 8; ++r)
                part[jg * 512 + r * 64 + (mh * 2 + mtp) * 16 + l15] = pr[mtp][r];
    }
    __syncthreads();                             // S5: partials ready, vt reads done

    // wn2 staging into freed vt region (all threads) || agg reduce (tid<512)
    {
        int oo = tid >> 4, kk = (tid & 15) << 2;
        *(float4*)&wn2[oo * 66 + kk] = *(const float4*)&Wn[oo * 128 + 64 + kk];
    }
    if (tid < 512) {
        int r = w, m = l;
        float s = 0.f;
#pragma unroll
        for (int q = 0; q < 8; ++q) s += part[q * 512 + r * 64 + m];
        s = fmaf(512.f, a_s[r * 68 + m], s);     // max-trick correction
        s = (maskf[iloc + r] == 0.f) ? s : 0.f;  // i-mask
        agg_s[r * 68 + m] = s;
    }
    __syncthreads();                             // S6: agg + wn2 ready

    // ---- epilogue: out = relu(o1 + agg·Wn2) ----
    if (tid < 512) {
        int r = w, m = l;
        float s = o1;
#pragma unroll
        for (int k = 0; k < 64; k += 4) {
            float4 h4 = *(float4*)&agg_s[r * 68 + k];   // wave-uniform broadcast
            float4 w4 = *(float4*)&wn2[m * 66 + k];
            s = fmaf(h4.x, w4.x, s); s = fmaf(h4.y, w4.y, s);
            s = fmaf(h4.z, w4.z, s); s = fmaf(h4.w, w4.w, s);
        }
        out[(i0 + r) * 64 + m] = fmaxf(s, 0.f);
    }
}

extern "C" void kernel_launch(void* const* d_in, const int* in_sizes, int n_in,
                              void* d_out, int out_size, void* d_ws, size_t ws_size,
                              hipStream_t stream) {
    const float* V    = (const float*)d_in[0];
    const int*   mask = (const int*)d_in[1];
    const float* Wmsg = (const float*)d_in[2];
    const float* bmsg = (const float*)d_in[3];
    const float* Wn   = (const float*)d_in[4];
    const float* bn   = (const float*)d_in[5];
    float* outp = (float*)d_out;

    const int BN = in_sizes[1];              // 2048
    fused_gb8<<<dim3(BN / 8), dim3(1024), 0, stream>>>(V, mask, Wmsg, bmsg, Wn, bn, outp);
}

// Round 9
// 20.152 us; speedup vs baseline: 1.2974x; 1.2974x over previous
//
#include <hip/hip_runtime.h>
#include <hip/hip_bf16.h>

// B=4, N=512, D=64. R9 = R7's MFMA structure re-geometried for TLP:
// 512 blocks x 4 i-rows x 512 thr (8 waves), __launch_bounds__(512,4) -> 2 blocks/CU,
// double-buffered vt (no stage<->compute serialization), 4 barriers (was 7).
//   wave w: mh=w>>2 (m-half: tiles {2mh,2mh+1}), jgg=w&3 (64 j per half = 4 t-tiles)
//   P1 (waves 0-3, MFMA): a = bmsg + V4·Wi (3-term hi/lo), o1 = bn? no: o1 acc (2-term), regs
//   P2: vt = bf16(V half-batch) XOR-swizzled LDS; acc = mfma(V_j, Wj_m)
//       p[r] += max(acc + maskf_j, -a[r][m])   (relu(a+c)=max(c,-a)+a; masked j -> -a -> 0)
//   reduce: shfl_xor(16,32) -> part[4][4][64] (overlays vt0) -> agg = sum + 512*a, i-mask
//   epi (waves 0-3, MFMA): out = relu(agg·Wn2 + o1 + bn)

typedef float  f32x4  __attribute__((ext_vector_type(4)));
typedef float  v2f    __attribute__((ext_vector_type(2)));
typedef short  bf16x8 __attribute__((ext_vector_type(8)));
typedef unsigned short u16;

__device__ __forceinline__ v2f pk_add(v2f a, v2f b) {
    v2f d; asm("v_pk_add_f32 %0, %1, %2" : "=v"(d) : "v"(a), "v"(b)); return d;
}
__device__ __forceinline__ u16 bf16_of(float x) {
    __hip_bfloat16 b = __float2bfloat16(x);
    return *(u16*)&b;
}
__device__ __forceinline__ bf16x8 cvt8(const float* p) {
    float4 x = *(const float4*)p, y = *(const float4*)(p + 4);
    float v[8] = {x.x, x.y, x.z, x.w, y.x, y.y, y.z, y.w};
    bf16x8 r;
#pragma unroll
    for (int i = 0; i < 8; ++i) r[i] = (short)bf16_of(v[i]);
    return r;
}
__device__ __forceinline__ void cvt8_hl(const float* p, bf16x8& h, bf16x8& l) {
    float4 x = *(const float4*)p, y = *(const float4*)(p + 4);
    float v[8] = {x.x, x.y, x.z, x.w, y.x, y.y, y.z, y.w};
#pragma unroll
    for (int i = 0; i < 8; ++i) {
        u16 hb = bf16_of(v[i]);
        h[i] = (short)hb;
        unsigned int u = (unsigned)hb << 16;
        l[i] = (short)bf16_of(v[i] - *(float*)&u);
    }
}

// LDS floats (17440 f = 69760 B; 2 blocks/CU: 139.5 KB <= 160 KB):
//   vt0 u16[256][64] @0 (8192 f) | overlay after S2: part f32[4][4][64] (1024 f)
//   vt1 u16[256][64] @8192 (8192 f)
//   maskf @16384 (512) | a_s[4][68] @16896 (272) | agg_s[4][68] @17168 (272)
__global__ __launch_bounds__(512, 4) void fused_gb9(
    const float* __restrict__ V, const int* __restrict__ mask,
    const float* __restrict__ Wmsg, const float* __restrict__ bmsg,
    const float* __restrict__ Wn, const float* __restrict__ bn,
    float* __restrict__ out)
{
    __shared__ float buf[17440];
    u16*   vt0   = (u16*)buf;
    u16*   vt1   = (u16*)(buf + 8192);
    float* part  = buf;
    float* maskf = buf + 16384;
    float* a_s   = buf + 16896;          // [4][68]
    float* agg_s = buf + 17168;          // [4][68]

    const int tid  = threadIdx.x;
    const int l    = tid & 63;
    const int w    = tid >> 6;           // 0..7
    const int g    = l >> 4;             // 0..3 k-group
    const int l15  = l & 15;
    const int mh   = w >> 2;             // 0..1 m-half
    const int jgg  = w & 3;              // 0..3 j-group (64 j per half)
    const int bb   = blockIdx.x >> 7;    // batch (128 blocks per batch)
    const int i0   = blockIdx.x * 4;
    const int iloc = (blockIdx.x & 127) * 4;
    const float* Vb = V + (size_t)bb * 512 * 64;

    // ---- stage vt (half h) -> bf16, XOR-swizzled ----
    auto stage_half = [&](int h, u16* vt) {
#pragma unroll
        for (int q = 0; q < 8; ++q) {
            int idx = tid + q * 512;             // 0..4095
            int row = idx >> 4;                  // 0..255
            int c4  = (idx & 15) << 2;           // float col 0,4,..,60
            float4 v4 = *(const float4*)&Vb[(h * 256 + row) * 64 + c4];
            ushort4 us;
            us.x = bf16_of(v4.x); us.y = bf16_of(v4.y);
            us.z = bf16_of(v4.z); us.w = bf16_of(v4.w);
            int byte = (row << 7) + ((c4 << 1) ^ ((row & 7) << 4));
            *(ushort4*)((char*)vt + byte) = us;
        }
    };

    stage_half(0, vt0);                          // issue V h0 at cycle 0
    maskf[tid] = mask[bb * 512 + tid] ? 0.f : -1e30f;

    // ---- bWj fragments (divergent global, L1/L2-resident -- R7-proven) ----
    bf16x8 bWj[2][2];
#pragma unroll
    for (int mtp = 0; mtp < 2; ++mtp) {
        int mrow = (mh * 2 + mtp) * 16 + l15;
#pragma unroll
        for (int kh = 0; kh < 2; ++kh)
            bWj[mtp][kh] = cvt8(Wmsg + mrow * 128 + 64 + (g << 3) + (kh << 5));
    }

    // ---- P1 (waves 0-3): a (3-term hi/lo) and o1 (2-term) via MFMA ----
    f32x4  acc_o1 = {0.f, 0.f, 0.f, 0.f};
    bf16x8 bWn2[2] = {};
    float  bn_m = 0.f;
    if (w < 4) {
        bf16x8 aVh[2], aVl[2], bWih[2], bWil[2], bWn1[2];
#pragma unroll
        for (int kh = 0; kh < 2; ++kh) {
            cvt8_hl(V + (i0 + (l15 & 3)) * 64 + (g << 3) + (kh << 5), aVh[kh], aVl[kh]);
            cvt8_hl(Wmsg + (w * 16 + l15) * 128 + (g << 3) + (kh << 5), bWih[kh], bWil[kh]);
            bWn1[kh] = cvt8(Wn + (w * 16 + l15) * 128 + (g << 3) + (kh << 5));
            bWn2[kh] = cvt8(Wn + (w * 16 + l15) * 128 + 64 + (g << 3) + (kh << 5));
        }
        f32x4 acc_a = {0.f, 0.f, 0.f, 0.f};
#pragma unroll
        for (int kh = 0; kh < 2; ++kh) {
            acc_a  = __builtin_amdgcn_mfma_f32_16x16x32_bf16(aVh[kh], bWih[kh], acc_a, 0, 0, 0);
            acc_a  = __builtin_amdgcn_mfma_f32_16x16x32_bf16(aVl[kh], bWih[kh], acc_a, 0, 0, 0);
            acc_a  = __builtin_amdgcn_mfma_f32_16x16x32_bf16(aVh[kh], bWil[kh], acc_a, 0, 0, 0);
            acc_o1 = __builtin_amdgcn_mfma_f32_16x16x32_bf16(aVh[kh], bWn1[kh], acc_o1, 0, 0, 0);
            acc_o1 = __builtin_amdgcn_mfma_f32_16x16x32_bf16(aVl[kh], bWn1[kh], acc_o1, 0, 0, 0);
        }
        float bm_m = bmsg[w * 16 + l15];
        bn_m = bn[w * 16 + l15];
        if (g == 0) {                            // D rows 0..3 = the block's 4 V rows
#pragma unroll
            for (int i = 0; i < 4; ++i)
                a_s[i * 68 + w * 16 + l15] = acc_a[i] + bm_m;
        }
    }
    __syncthreads();                             // S1: vt0, maskf, a_s ready

    float nar[2][4];
#pragma unroll
    for (int mtp = 0; mtp < 2; ++mtp) {
        int m = (mh * 2 + mtp) * 16 + l15;
#pragma unroll
        for (int r = 0; r < 4; ++r) nar[mtp][r] = -a_s[r * 68 + m];
    }
    v2f p2[2][4];
#pragma unroll
    for (int mtp = 0; mtp < 2; ++mtp)
#pragma unroll
        for (int r = 0; r < 4; ++r) p2[mtp][r] = (v2f){0.f, 0.f};

    auto compute_half = [&](int h, const u16* vt) {
#pragma unroll
        for (int t = 0; t < 4; ++t) {
            int jbase = jgg * 64 + t * 16;
            bf16x8 aV[2];
#pragma unroll
            for (int kh = 0; kh < 2; ++kh) {
                int jrow = jbase + l15;
                int byte = (jrow << 7) + ((((g << 4) + (kh << 6))) ^ ((jrow & 7) << 4));
                aV[kh] = *(const bf16x8*)((const char*)vt + byte);
            }
            f32x4 mf = *(const f32x4*)&maskf[h * 256 + jbase + g * 4];  // lane's 4 j's
#pragma unroll
            for (int mtp = 0; mtp < 2; ++mtp) {
                f32x4 acc = {0.f, 0.f, 0.f, 0.f};
                acc = __builtin_amdgcn_mfma_f32_16x16x32_bf16(aV[0], bWj[mtp][0], acc, 0, 0, 0);
                acc = __builtin_amdgcn_mfma_f32_16x16x32_bf16(aV[1], bWj[mtp][1], acc, 0, 0, 0);
                float cm0 = acc[0] + mf[0], cm1 = acc[1] + mf[1];
                float cm2 = acc[2] + mf[2], cm3 = acc[3] + mf[3];
#pragma unroll
                for (int r = 0; r < 4; ++r) {
                    float n = nar[mtp][r];
                    v2f mxa = { fmaxf(cm0, n), fmaxf(cm1, n) };
                    v2f mxb = { fmaxf(cm2, n), fmaxf(cm3, n) };
                    p2[mtp][r] = pk_add(p2[mtp][r], mxa);
                    p2[mtp][r] = pk_add(p2[mtp][r], mxb);
                }
            }
        }
    };

    stage_half(1, vt1);                          // issue h1 loads; overlap with compute h0
    compute_half(0, vt0);
    __syncthreads();                             // S2: vt0 reads done, vt1 ready
    compute_half(1, vt1);

    // in-wave reduce over g (lane^16, ^32); part overlays vt0 (free after S2)
    float pr[2][4];
#pragma unroll
    for (int mtp = 0; mtp < 2; ++mtp)
#pragma unroll
        for (int r = 0; r < 4; ++r) {
            float v = p2[mtp][r].x + p2[mtp][r].y;
            v += __shfl_xor(v, 16);
            v += __shfl_xor(v, 32);
            pr[mtp][r] = v;
        }
    if (l < 16) {
#pragma unroll
        for (int mtp = 0; mtp < 2; ++mtp)
#pragma unroll
            for (int r = 0; r < 4; ++r)
                part[jgg * 256 + r * 64 + (mh * 2 + mtp) * 16 + l15] = pr[mtp][r];
    }
    __syncthreads();                             // S3: partials ready

    if (tid < 256) {
        int r = tid >> 6, m = tid & 63;
        float s = part[r * 64 + m] + part[256 + r * 64 + m]
                + part[512 + r * 64 + m] + part[768 + r * 64 + m];
        s = fmaf(512.f, a_s[r * 68 + m], s);     // max-trick correction
        s = (maskf[iloc + r] == 0.f) ? s : 0.f;  // i-mask
        agg_s[r * 68 + m] = s;
    }
    __syncthreads();                             // S4: agg ready

    // ---- epilogue MFMA (waves 0-3): out = relu(agg·Wn2 + o1 + bn) ----
    if (w < 4) {
        bf16x8 aAgg[2];
#pragma unroll
        for (int kh = 0; kh < 2; ++kh)
            aAgg[kh] = cvt8(&agg_s[(l15 & 3) * 68 + (g << 3) + (kh << 5)]);
        f32x4 accO = acc_o1;
        accO = __builtin_amdgcn_mfma_f32_16x16x32_bf16(aAgg[0], bWn2[0], accO, 0, 0, 0);
        accO = __builtin_amdgcn_mfma_f32_16x16x32_bf16(aAgg[1], bWn2[1], accO, 0, 0, 0);
        if (g == 0) {
#pragma unroll
            for (int i = 0; i < 4; ++i)
                out[(i0 + i) * 64 + w * 16 + l15] = fmaxf(accO[i] + bn_m, 0.f);
        }
    }
}

extern "C" void kernel_launch(void* const* d_in, const int* in_sizes, int n_in,
                              void* d_out, int out_size, void* d_ws, size_t ws_size,
                              hipStream_t stream) {
    const float* V    = (const float*)d_in[0];
    const int*   mask = (const int*)d_in[1];
    const float* Wmsg = (const float*)d_in[2];
    const float* bmsg = (const float*)d_in[3];
    const float* Wn   = (const float*)d_in[4];
    const float* bn   = (const float*)d_in[5];
    float* outp = (float*)d_out;

    const int BN = in_sizes[1];                  // 2048
    fused_gb9<<<dim3(BN / 4), dim3(512), 0, stream>>>(V, mask, Wmsg, bmsg, Wn, bn, outp);
}

// Round 10
// 17.788 us; speedup vs baseline: 1.4698x; 1.1329x over previous
//
#include <hip/hip_runtime.h>
#include <hip/hip_bf16.h>

// B=4, N=512, D=64. R10 = R7 (best, 18.4us) + double-buffered vt (stage h1
// overlaps compute h0; barriers 7 -> 4). 256 blocks x 1024 thr (16 waves),
// 8 i-rows/block, no inter-block deps.
//   wave w: mh=w>>3 (m-half: tiles {2mh,2mh+1}), jg=w&7 (32 j per half-batch)
//   P1 (waves 0-3, MFMA): a = bmsg + V8·Wi (3-term hi/lo), o1 = V8·Wn1 (2-term, regs)
//   P2: vt = bf16(V half-batch) XOR-swizzled LDS; acc = mfma(V_j, Wj_m)
//       p[r] += max(acc + maskf_j, -a[r][m])  (relu(a+c)=max(c,-a)+a; masked j -> -a -> 0)
//   reduce: shfl_xor(16,32) -> part[8][8][64] (overlays vt0) -> agg = sum + 512*a, i-mask
//   epi (waves 0-3, MFMA): out = relu(agg·Wn2 + o1 + bn)

typedef float  f32x4  __attribute__((ext_vector_type(4)));
typedef float  v2f    __attribute__((ext_vector_type(2)));
typedef short  bf16x8 __attribute__((ext_vector_type(8)));
typedef unsigned short u16;

__device__ __forceinline__ v2f pk_add(v2f a, v2f b) {
    v2f d; asm("v_pk_add_f32 %0, %1, %2" : "=v"(d) : "v"(a), "v"(b)); return d;
}
__device__ __forceinline__ u16 bf16_of(float x) {
    __hip_bfloat16 b = __float2bfloat16(x);
    return *(u16*)&b;
}
__device__ __forceinline__ bf16x8 cvt8(const float* p) {
    float4 x = *(const float4*)p, y = *(const float4*)(p + 4);
    float v[8] = {x.x, x.y, x.z, x.w, y.x, y.y, y.z, y.w};
    bf16x8 r;
#pragma unroll
    for (int i = 0; i < 8; ++i) r[i] = (short)bf16_of(v[i]);
    return r;
}
__device__ __forceinline__ void cvt8_hl(const float* p, bf16x8& h, bf16x8& l) {
    float4 x = *(const float4*)p, y = *(const float4*)(p + 4);
    float v[8] = {x.x, x.y, x.z, x.w, y.x, y.y, y.z, y.w};
#pragma unroll
    for (int i = 0; i < 8; ++i) {
        u16 hb = bf16_of(v[i]);
        h[i] = (short)hb;
        unsigned int u = (unsigned)hb << 16;
        l[i] = (short)bf16_of(v[i] - *(float*)&u);
    }
}

// LDS floats (17984 f = 71936 B, 1 block/CU):
//   vt0 u16[256][64] @0 (8192 f) | overlay after S2: part f32[8][8][64] (4096 f)
//   vt1 u16[256][64] @8192 (8192 f)
//   maskf @16384 (512) | a_s[8][68] @16896 (544) | agg_s[8][68] @17440 (544)
__global__ __launch_bounds__(1024) void fused_gb10(
    const float* __restrict__ V, const int* __restrict__ mask,
    const float* __restrict__ Wmsg, const float* __restrict__ bmsg,
    const float* __restrict__ Wn, const float* __restrict__ bn,
    float* __restrict__ out)
{
    __shared__ float buf[17984];
    u16*   vt0   = (u16*)buf;
    u16*   vt1   = (u16*)(buf + 8192);
    float* part  = buf;
    float* maskf = buf + 16384;
    float* a_s   = buf + 16896;          // [8][68]
    float* agg_s = buf + 17440;          // [8][68]

    const int tid  = threadIdx.x;
    const int l    = tid & 63;
    const int w    = tid >> 6;           // 0..15
    const int g    = l >> 4;             // 0..3 k-group
    const int l15  = l & 15;
    const int mh   = w >> 3;             // 0..1 m-half
    const int jg   = w & 7;              // 0..7 j-group
    const int bb   = blockIdx.x >> 6;    // batch (64 blocks per batch)
    const int i0   = blockIdx.x * 8;
    const int iloc = (blockIdx.x & 63) * 8;
    const float* Vb = V + (size_t)bb * 512 * 64;

    // ---- stage vt (half h) -> bf16, XOR-swizzled ----
    auto stage_half = [&](int h, u16* vt) {
#pragma unroll
        for (int q = 0; q < 4; ++q) {
            int idx = tid + q * 1024;            // 0..4095
            int row = idx >> 4;                  // 0..255
            int c4  = (idx & 15) << 2;           // float col 0,4,..,60
            float4 v4 = *(const float4*)&Vb[(h * 256 + row) * 64 + c4];
            ushort4 us;
            us.x = bf16_of(v4.x); us.y = bf16_of(v4.y);
            us.z = bf16_of(v4.z); us.w = bf16_of(v4.w);
            int byte = (row << 7) + ((c4 << 1) ^ ((row & 7) << 4));
            *(ushort4*)((char*)vt + byte) = us;
        }
    };

    stage_half(0, vt0);                          // issue V h0 at cycle 0
    if (tid < 512) maskf[tid] = mask[bb * 512 + tid] ? 0.f : -1e30f;

    // ---- Wj B-frags (divergent global, L1/L2-resident -- R7-proven) ----
    bf16x8 bWj[2][2];
#pragma unroll
    for (int mtp = 0; mtp < 2; ++mtp) {
        int mrow = (mh * 2 + mtp) * 16 + l15;
#pragma unroll
        for (int kh = 0; kh < 2; ++kh)
            bWj[mtp][kh] = cvt8(Wmsg + mrow * 128 + 64 + (g << 3) + (kh << 5));
    }

    // ---- P1 (waves 0-3): a (3-term hi/lo) and o1 (2-term) via MFMA ----
    f32x4  acc_o1 = {0.f, 0.f, 0.f, 0.f};
    bf16x8 bWn2[2] = {};
    float  bn_m = 0.f;
    if (w < 4) {
        bf16x8 aVh[2], aVl[2], bWih[2], bWil[2], bWn1[2];
#pragma unroll
        for (int kh = 0; kh < 2; ++kh) {
            cvt8_hl(V + (i0 + (l15 & 7)) * 64 + (g << 3) + (kh << 5), aVh[kh], aVl[kh]);
            cvt8_hl(Wmsg + (w * 16 + l15) * 128 + (g << 3) + (kh << 5), bWih[kh], bWil[kh]);
            bWn1[kh] = cvt8(Wn + (w * 16 + l15) * 128 + (g << 3) + (kh << 5));
            bWn2[kh] = cvt8(Wn + (w * 16 + l15) * 128 + 64 + (g << 3) + (kh << 5));
        }
        f32x4 acc_a = {0.f, 0.f, 0.f, 0.f};
#pragma unroll
        for (int kh = 0; kh < 2; ++kh) {
            acc_a  = __builtin_amdgcn_mfma_f32_16x16x32_bf16(aVh[kh], bWih[kh], acc_a, 0, 0, 0);
            acc_a  = __builtin_amdgcn_mfma_f32_16x16x32_bf16(aVl[kh], bWih[kh], acc_a, 0, 0, 0);
            acc_a  = __builtin_amdgcn_mfma_f32_16x16x32_bf16(aVh[kh], bWil[kh], acc_a, 0, 0, 0);
            acc_o1 = __builtin_amdgcn_mfma_f32_16x16x32_bf16(aVh[kh], bWn1[kh], acc_o1, 0, 0, 0);
            acc_o1 = __builtin_amdgcn_mfma_f32_16x16x32_bf16(aVl[kh], bWn1[kh], acc_o1, 0, 0, 0);
        }
        float bm_m = bmsg[w * 16 + l15];
        bn_m = bn[w * 16 + l15];
        if (g < 2) {
#pragma unroll
            for (int i = 0; i < 4; ++i)
                a_s[(g * 4 + i) * 68 + w * 16 + l15] = acc_a[i] + bm_m;
        }
    }
    __syncthreads();                             // S1: vt0, maskf, a_s ready

    stage_half(1, vt1);                          // issue h1; overlaps compute h0

    float nar[2][8];
#pragma unroll
    for (int mtp = 0; mtp < 2; ++mtp) {
        int m = (mh * 2 + mtp) * 16 + l15;
#pragma unroll
        for (int r = 0; r < 8; ++r) nar[mtp][r] = -a_s[r * 68 + m];
    }
    v2f p2[2][8];
#pragma unroll
    for (int mtp = 0; mtp < 2; ++mtp)
#pragma unroll
        for (int r = 0; r < 8; ++r) p2[mtp][r] = (v2f){0.f, 0.f};

    auto compute_half = [&](int h, const u16* vt) {
#pragma unroll
        for (int t = 0; t < 2; ++t) {
            int jbase = jg * 32 + t * 16;
            bf16x8 aV[2];
#pragma unroll
            for (int kh = 0; kh < 2; ++kh) {
                int jrow = jbase + l15;
                int byte = (jrow << 7) + ((((g << 4) + (kh << 6))) ^ ((jrow & 7) << 4));
                aV[kh] = *(const bf16x8*)((const char*)vt + byte);
            }
            f32x4 mf = *(const f32x4*)&maskf[h * 256 + jbase + g * 4];  // lane's 4 j's
#pragma unroll
            for (int mtp = 0; mtp < 2; ++mtp) {
                f32x4 acc = {0.f, 0.f, 0.f, 0.f};
                acc = __builtin_amdgcn_mfma_f32_16x16x32_bf16(aV[0], bWj[mtp][0], acc, 0, 0, 0);
                acc = __builtin_amdgcn_mfma_f32_16x16x32_bf16(aV[1], bWj[mtp][1], acc, 0, 0, 0);
                float cm0 = acc[0] + mf[0], cm1 = acc[1] + mf[1];
                float cm2 = acc[2] + mf[2], cm3 = acc[3] + mf[3];
#pragma unroll
                for (int r = 0; r < 8; ++r) {
                    float n = nar[mtp][r];
                    v2f mxa = { fmaxf(cm0, n), fmaxf(cm1, n) };
                    v2f mxb = { fmaxf(cm2, n), fmaxf(cm3, n) };
                    p2[mtp][r] = pk_add(p2[mtp][r], mxa);
                    p2[mtp][r] = pk_add(p2[mtp][r], mxb);
                }
            }
        }
    };

    compute_half(0, vt0);
    __syncthreads();                             // S2: vt0 reads done, vt1 writes done
    compute_half(1, vt1);

    // in-wave reduce over g (lane^16, ^32); part overlays vt0 (free after S2)
    float pr[2][8];
#pragma unroll
    for (int mtp = 0; mtp < 2; ++mtp)
#pragma unroll
        for (int r = 0; r < 8; ++r) {
            float v = p2[mtp][r].x + p2[mtp][r].y;
            v += __shfl_xor(v, 16);
            v += __shfl_xor(v, 32);
            pr[mtp][r] = v;
        }
    if (l < 16) {
#pragma unroll
        for (int mtp = 0; mtp < 2; ++mtp)
#pragma unroll
            for (int r = 0; r < 8; ++r)
                part[jg * 512 + r * 64 + (mh * 2 + mtp) * 16 + l15] = pr[mtp][r];
    }
    __syncthreads();                             // S3: partials ready

    if (tid < 512) {
        int r = w, m = l;
        float s = 0.f;
#pragma unroll
        for (int q = 0; q < 8; ++q) s += part[q * 512 + r * 64 + m];
        s = fmaf(512.f, a_s[r * 68 + m], s);     // max-trick correction
        s = (maskf[iloc + r] == 0.f) ? s : 0.f;  // i-mask
        agg_s[r * 68 + m] = s;
    }
    __syncthreads();                             // S4: agg ready

    // ---- epilogue MFMA (waves 0-3): out = relu(agg·Wn2 + o1 + bn) ----
    if (w < 4) {
        bf16x8 aAgg[2];
#pragma unroll
        for (int kh = 0; kh < 2; ++kh)
            aAgg[kh] = cvt8(&agg_s[(l15 & 7) * 68 + (g << 3) + (kh << 5)]);
        f32x4 accO = acc_o1;
        accO = __builtin_amdgcn_mfma_f32_16x16x32_bf16(aAgg[0], bWn2[0], accO, 0, 0, 0);
        accO = __builtin_amdgcn_mfma_f32_16x16x32_bf16(aAgg[1], bWn2[1], accO, 0, 0, 0);
        if (g < 2) {
#pragma unroll
            for (int i = 0; i < 4; ++i)
                out[(i0 + g * 4 + i) * 64 + w * 16 + l15] = fmaxf(accO[i] + bn_m, 0.f);
        }
    }
}

extern "C" void kernel_launch(void* const* d_in, const int* in_sizes, int n_in,
                              void* d_out, int out_size, void* d_ws, size_t ws_size,
                              hipStream_t stream) {
    const float* V    = (const float*)d_in[0];
    const int*   mask = (const int*)d_in[1];
    const float* Wmsg = (const float*)d_in[2];
    const float* bmsg = (const float*)d_in[3];
    const float* Wn   = (const float*)d_in[4];
    const float* bn   = (const float*)d_in[5];
    float* outp = (float*)d_out;

    const int BN = in_sizes[1];                  // 2048
    fused_gb10<<<dim3(BN / 8), dim3(1024), 0, stream>>>(V, mask, Wmsg, bmsg, Wn, bn, outp);
}